// Round 6
// baseline (29979.443 us; speedup 1.0000x reference)
//
#include <hip/hip_runtime.h>

typedef _Float16 f16;
typedef f16 f16x2 __attribute__((ext_vector_type(2)));
typedef f16 f16x4 __attribute__((ext_vector_type(4)));
typedef f16 f16x8 __attribute__((ext_vector_type(8)));
typedef float f32x4 __attribute__((ext_vector_type(4)));
typedef unsigned int u32;
typedef unsigned short u16;
typedef unsigned long long u64;

#define R 4096
#define IN_DIM 256
#define T_STEPS 4096
#define NBLK 256
#define TPB 1024
#define WPB 16

// ---- W f32 -> fp16 conversion (re-run every call; deterministic) ----
__global__ void wconv_kernel(const float* __restrict__ W, f16* __restrict__ Wh) {
    size_t i = ((size_t)blockIdx.x * 256 + threadIdx.x) * 4;
    f32x4 v = *(const f32x4*)(W + i);
    f16x4 o = { (f16)v.x, (f16)v.y, (f16)v.z, (f16)v.w };
    *(f16x4*)(Wh + i) = o;
}

// ---- persistent scan: 256 blocks x 16 waves, 1 row/wave, W in VGPRs.
// h exchanged as SELF-VALIDATING u32 words: (tag << 16) | f16bits.
// One atomic u32 store per row per step; consumer poll IS the data load. ----
__global__ __launch_bounds__(TPB) void esn_kernel(
    const float* __restrict__ x,      // [T][256]
    const float* __restrict__ Win,    // [R][256]
    const f16*   __restrict__ W,      // [R][R] fp16
    u32* hw0, u32* hw1,               // [R] tagged h words, double-buffered
    const float* __restrict__ Wout,   // [256][R]
    const float* __restrict__ bias,   // [256]
    float* __restrict__ out)          // [256]
{
    __shared__ f16   h_lds[2][R];     // 16 KB, parity double-buffered
    __shared__ float x_lds[2][IN_DIM];
    __shared__ float red[WPB];

    const int tid  = threadIdx.x;
    const int b    = blockIdx.x;
    const int wave = tid >> 6;
    const int lane = tid & 63;
    const int row  = b * WPB + wave;

    // one-time preload: W row (32 VGPRs) + Win fragment (4 VGPRs)
    f16x8 wreg[8];
    {
        const f16* wrow = W + (size_t)row * R;
#pragma unroll
        for (int c = 0; c < 8; ++c)
            wreg[c] = *(const f16x8*)(wrow + (c * 64 + lane) * 8);
    }
    const f32x4 winreg = *(const f32x4*)(Win + (size_t)row * IN_DIM + lane * 4);

    for (int t = 0; t < T_STEPS; ++t) {
        const int p = t & 1;
        const u32* h_in  = p ? hw1 : hw0;
        u32*       h_out = p ? hw0 : hw1;

        // issue x[t] fragment load early; latency hides under the poll
        float xv = 0.f;
        if (tid < IN_DIM) xv = x[(size_t)t * IN_DIM + tid];

        // ---- fused poll+load: 4 rows/thread, 2 u64 loads, validate 4 tags ----
        {
            const u64* hp = (const u64*)h_in + (size_t)tid * 2;
            const u64 tt = (u64)t;
            u64 a, c;
            for (;;) {
                a = __hip_atomic_load(hp,     __ATOMIC_RELAXED, __HIP_MEMORY_SCOPE_AGENT);
                c = __hip_atomic_load(hp + 1, __ATOMIC_RELAXED, __HIP_MEMORY_SCOPE_AGENT);
                bool ok = (((a >> 16) & 0xffffu) == tt) & ((a >> 48) == tt)
                        & (((c >> 16) & 0xffffu) == tt) & ((c >> 48) == tt);
                if (ok) break;
                __builtin_amdgcn_s_sleep(1);
            }
            // extract 4 f16 payloads -> 8 B into LDS
            u32 lo = (u32)(a & 0xffffu) | (((u32)(a >> 32) & 0xffffu) << 16);
            u32 hi = (u32)(c & 0xffffu) | (((u32)(c >> 32) & 0xffffu) << 16);
            u32* hl = (u32*)h_lds[p];
            hl[tid * 2 + 0] = lo;
            hl[tid * 2 + 1] = hi;
        }
        if (tid < IN_DIM) x_lds[p][tid] = xv;
        __syncthreads();  // the ONLY barrier per step

        // ---- dot(W[row,:], h): 8 ds_read_b128 + 32 fdot2, 4 acc chains ----
        float a0 = 0.f, a1 = 0.f, a2 = 0.f, a3 = 0.f;
#pragma unroll
        for (int c = 0; c < 8; ++c) {
            const f16x8 hv = *(const f16x8*)(&h_lds[p][(c * 64 + lane) * 8]);
            const f16x2 h0 = { hv[0], hv[1] }, h1 = { hv[2], hv[3] };
            const f16x2 h2 = { hv[4], hv[5] }, h3 = { hv[6], hv[7] };
            const f16x2 w0 = { wreg[c][0], wreg[c][1] }, w1 = { wreg[c][2], wreg[c][3] };
            const f16x2 w2 = { wreg[c][4], wreg[c][5] }, w3 = { wreg[c][6], wreg[c][7] };
            a0 = __builtin_amdgcn_fdot2(w0, h0, a0, false);
            a1 = __builtin_amdgcn_fdot2(w1, h1, a1, false);
            a2 = __builtin_amdgcn_fdot2(w2, h2, a2, false);
            a3 = __builtin_amdgcn_fdot2(w3, h3, a3, false);
        }
        float acc = (a0 + a1) + (a2 + a3);
        {
            const f32x4 xf = *(const f32x4*)(&x_lds[p][lane * 4]);
            acc = fmaf(winreg.x, xf.x, acc);
            acc = fmaf(winreg.y, xf.y, acc);
            acc = fmaf(winreg.z, xf.z, acc);
            acc = fmaf(winreg.w, xf.w, acc);
        }
#pragma unroll
        for (int off = 32; off > 0; off >>= 1)
            acc += __shfl_xor(acc, off, 64);

        // ---- publish: one self-validating u32 per row, immediately ----
        if (lane == 0) {
            f16 hf = (f16)tanhf(acc);
            u16 bits;
            __builtin_memcpy(&bits, &hf, 2);
            u32 word = ((u32)(t + 1) << 16) | (u32)bits;
            __hip_atomic_store(h_out + row, word, __ATOMIC_RELAXED,
                               __HIP_MEMORY_SCOPE_AGENT);
        }
        // no trailing barrier: next poll + parity-buffered LDS gate reuse
    }

    // ---- epilogue: poll h_T (tag = T_STEPS, parity 0), Wout matvec ----
    {
        const u64* hp = (const u64*)hw0 + (size_t)tid * 2;
        const u64 tt = (u64)T_STEPS;
        u64 a, c;
        for (;;) {
            a = __hip_atomic_load(hp,     __ATOMIC_RELAXED, __HIP_MEMORY_SCOPE_AGENT);
            c = __hip_atomic_load(hp + 1, __ATOMIC_RELAXED, __HIP_MEMORY_SCOPE_AGENT);
            bool ok = (((a >> 16) & 0xffffu) == tt) & ((a >> 48) == tt)
                    & (((c >> 16) & 0xffffu) == tt) & ((c >> 48) == tt);
            if (ok) break;
            __builtin_amdgcn_s_sleep(1);
        }
        u32 lo = (u32)(a & 0xffffu) | (((u32)(a >> 32) & 0xffffu) << 16);
        u32 hi = (u32)(c & 0xffffu) | (((u32)(c >> 32) & 0xffffu) << 16);
        u32* hl = (u32*)h_lds[0];
        hl[tid * 2 + 0] = lo;
        hl[tid * 2 + 1] = hi;
    }
    __syncthreads();
    {
        const float* worow = Wout + (size_t)b * R;
        const f32x4 wv = *(const f32x4*)(worow + tid * 4);
        const f16* hf = h_lds[0];
        float acc = wv.x * (float)hf[tid * 4 + 0]
                  + wv.y * (float)hf[tid * 4 + 1]
                  + wv.z * (float)hf[tid * 4 + 2]
                  + wv.w * (float)hf[tid * 4 + 3];
#pragma unroll
        for (int off = 32; off > 0; off >>= 1)
            acc += __shfl_xor(acc, off, 64);
        if (lane == 0) red[wave] = acc;
        __syncthreads();
        if (tid == 0) {
            float s = bias[b];
#pragma unroll
            for (int w = 0; w < WPB; ++w) s += red[w];
            out[b] = s;
        }
    }
}

extern "C" void kernel_launch(void* const* d_in, const int* in_sizes, int n_in,
                              void* d_out, int out_size, void* d_ws, size_t ws_size,
                              hipStream_t stream) {
    const float* x    = (const float*)d_in[0];
    const float* Win  = (const float*)d_in[1];
    const float* W    = (const float*)d_in[2];
    const float* Wout = (const float*)d_in[3];
    const float* bias = (const float*)d_in[4];
    float* out = (float*)d_out;

    char* ws = (char*)d_ws;
    u32* hw0 = (u32*)ws;                   // 16 KB tagged h words, parity 0
    u32* hw1 = (u32*)(ws + 16384);         // 16 KB tagged h words, parity 1
    f16* Wh  = (f16*)(ws + 65536);         // 32 MB fp16 W

    // zero both tagged-h buffers: h_0 = 0 with tag 0 comes for free
    hipMemsetAsync(ws, 0, 65536, stream);

    wconv_kernel<<<(R * (size_t)R) / (256 * 4), 256, 0, stream>>>(W, Wh);
    esn_kernel<<<NBLK, TPB, 0, stream>>>(x, Win, Wh, hw0, hw1,
                                         Wout, bias, out);
}

// Round 7
// 11823.202 us; speedup vs baseline: 2.5356x; 2.5356x over previous
//
#include <hip/hip_runtime.h>

typedef _Float16 f16;
typedef f16 f16x2 __attribute__((ext_vector_type(2)));
typedef f16 f16x4 __attribute__((ext_vector_type(4)));
typedef f16 f16x8 __attribute__((ext_vector_type(8)));
typedef float f32x4 __attribute__((ext_vector_type(4)));
typedef unsigned int u32;
typedef unsigned short u16;
typedef unsigned long long u64;

#define R 4096
#define IN_DIM 256
#define T_STEPS 4096
#define NBLK 256
#define TPB 1024
#define WPB 16

// ---- W f32 -> fp16 conversion (re-run every call; deterministic) ----
__global__ void wconv_kernel(const float* __restrict__ W, f16* __restrict__ Wh) {
    size_t i = ((size_t)blockIdx.x * 256 + threadIdx.x) * 4;
    f32x4 v = *(const f32x4*)(W + i);
    f16x4 o = { (f16)v.x, (f16)v.y, (f16)v.z, (f16)v.w };
    *(f16x4*)(Wh + i) = o;
}

// ---- persistent scan: 256 blocks x 16 waves, 1 row/wave, W in VGPRs.
// h exchanged as self-validating u64 GRANULES (tag<<48 | 2 f16 rows),
// published as ONE 64B burst per block per step (8 u64 from wave 15).
// Consumer poll IS the data load: one one-way visibility hop per step. ----
__global__ __launch_bounds__(TPB) void esn_kernel(
    const float* __restrict__ x,      // [T][256]
    const float* __restrict__ Win,    // [R][256]
    const f16*   __restrict__ W,      // [R][R] fp16
    u64* hg0, u64* hg1,               // [R/2] tagged granules, double-buffered
    const float* __restrict__ Wout,   // [256][R]
    const float* __restrict__ bias,   // [256]
    float* __restrict__ out)          // [256]
{
    __shared__ f16   h_lds[2][R];     // 16 KB, parity double-buffered
    __shared__ float x_lds[2][IN_DIM];
    __shared__ u32   red_tag[WPB];    // tagged LDS relay words
    __shared__ float red_f[WPB];      // epilogue reduction

    const int tid  = threadIdx.x;
    const int b    = blockIdx.x;
    const int wave = tid >> 6;
    const int lane = tid & 63;
    const int row  = b * WPB + wave;

    // zero the LDS relay (LDS contents are undefined across launches!)
    if (tid < WPB) red_tag[tid] = 0;

    // one-time preload: W row (32 VGPRs) + Win fragment (4 VGPRs)
    f16x8 wreg[8];
    {
        const f16* wrow = W + (size_t)row * R;
#pragma unroll
        for (int c = 0; c < 8; ++c)
            wreg[c] = *(const f16x8*)(wrow + (c * 64 + lane) * 8);
    }
    const f32x4 winreg = *(const f32x4*)(Win + (size_t)row * IN_DIM + lane * 4);
    __syncthreads();

    for (int t = 0; t < T_STEPS; ++t) {
        const int p = t & 1;
        const u64* g_in  = p ? hg1 : hg0;
        u64*       g_out = p ? hg0 : hg1;

        // issue x[t] fragment load early; latency hides under the poll
        float xv = 0.f;
        if (tid < IN_DIM) xv = x[(size_t)t * IN_DIM + tid];

        // ---- fused poll+load: thread owns u64s 2tid,2tid+1 (rows 4tid..4tid+3)
        {
            const u64* gp = g_in + (size_t)tid * 2;
            const u64 tt = (u64)(u32)t;
            u64 g0, g1;
            for (;;) {
                g0 = __hip_atomic_load(gp,     __ATOMIC_RELAXED, __HIP_MEMORY_SCOPE_AGENT);
                g1 = __hip_atomic_load(gp + 1, __ATOMIC_RELAXED, __HIP_MEMORY_SCOPE_AGENT);
                if (((g0 >> 48) == tt) & ((g1 >> 48) == tt)) break;
                __builtin_amdgcn_s_sleep(1);
            }
            u32* hl = (u32*)h_lds[p];
            hl[tid * 2 + 0] = (u32)g0;   // rows 4tid, 4tid+1 (packed f16x2)
            hl[tid * 2 + 1] = (u32)g1;   // rows 4tid+2, 4tid+3
        }
        if (tid < IN_DIM) x_lds[p][tid] = xv;
        __syncthreads();  // the ONLY barrier per step

        // ---- dot(W[row,:], h): 8 ds_read_b128 + 32 fdot2, 4 acc chains ----
        float a0 = 0.f, a1 = 0.f, a2 = 0.f, a3 = 0.f;
#pragma unroll
        for (int c = 0; c < 8; ++c) {
            const f16x8 hv = *(const f16x8*)(&h_lds[p][(c * 64 + lane) * 8]);
            const f16x2 h0 = { hv[0], hv[1] }, h1 = { hv[2], hv[3] };
            const f16x2 h2 = { hv[4], hv[5] }, h3 = { hv[6], hv[7] };
            const f16x2 w0 = { wreg[c][0], wreg[c][1] }, w1 = { wreg[c][2], wreg[c][3] };
            const f16x2 w2 = { wreg[c][4], wreg[c][5] }, w3 = { wreg[c][6], wreg[c][7] };
            a0 = __builtin_amdgcn_fdot2(w0, h0, a0, false);
            a1 = __builtin_amdgcn_fdot2(w1, h1, a1, false);
            a2 = __builtin_amdgcn_fdot2(w2, h2, a2, false);
            a3 = __builtin_amdgcn_fdot2(w3, h3, a3, false);
        }
        float acc = (a0 + a1) + (a2 + a3);
        {
            const f32x4 xf = *(const f32x4*)(&x_lds[p][lane * 4]);
            acc = fmaf(winreg.x, xf.x, acc);
            acc = fmaf(winreg.y, xf.y, acc);
            acc = fmaf(winreg.z, xf.z, acc);
            acc = fmaf(winreg.w, xf.w, acc);
        }
#pragma unroll
        for (int off = 32; off > 0; off >>= 1)
            acc += __shfl_xor(acc, off, 64);

        // ---- tagged LDS relay: lane 0 posts (tag<<16 | f16bits) ----
        if (lane == 0) {
            f16 hf = (f16)tanhf(acc);
            u16 bits;
            __builtin_memcpy(&bits, &hf, 2);
            __hip_atomic_store(&red_tag[wave], ((u32)(t + 1) << 16) | (u32)bits,
                               __ATOMIC_RELAXED, __HIP_MEMORY_SCOPE_WORKGROUP);
        }

        // ---- wave 15: gather 16 relay words, pack 8 granules, ONE burst ----
        if (wave == WPB - 1) {
            u32 myw = 0;
            if (lane < WPB) {
                do {
                    myw = __hip_atomic_load(&red_tag[lane], __ATOMIC_RELAXED,
                                            __HIP_MEMORY_SCOPE_WORKGROUP);
                } while ((myw >> 16) != (u32)(t + 1));
            }
            const u32 wa = (u32)__shfl((int)myw, lane * 2,     64);
            const u32 wb = (u32)__shfl((int)myw, lane * 2 + 1, 64);
            if (lane < 8) {
                const u64 g = ((u64)(u32)(t + 1) << 48)
                            | ((u64)(wb & 0xffffu) << 16)
                            | ((u64)(wa & 0xffffu));
                __hip_atomic_store(g_out + b * 8 + lane, g,
                                   __ATOMIC_RELAXED, __HIP_MEMORY_SCOPE_AGENT);
            }
        }
        // no trailing barrier: next poll + parity LDS double-buffer gate reuse
    }

    // ---- epilogue: poll h_T (tag = T_STEPS, parity 0), Wout matvec ----
    {
        const u64* gp = hg0 + (size_t)tid * 2;
        const u64 tt = (u64)(u32)T_STEPS;
        u64 g0, g1;
        for (;;) {
            g0 = __hip_atomic_load(gp,     __ATOMIC_RELAXED, __HIP_MEMORY_SCOPE_AGENT);
            g1 = __hip_atomic_load(gp + 1, __ATOMIC_RELAXED, __HIP_MEMORY_SCOPE_AGENT);
            if (((g0 >> 48) == tt) & ((g1 >> 48) == tt)) break;
            __builtin_amdgcn_s_sleep(1);
        }
        u32* hl = (u32*)h_lds[0];
        hl[tid * 2 + 0] = (u32)g0;
        hl[tid * 2 + 1] = (u32)g1;
    }
    __syncthreads();
    {
        const float* worow = Wout + (size_t)b * R;
        const f32x4 wv = *(const f32x4*)(worow + tid * 4);
        const f16* hf = h_lds[0];
        float acc = wv.x * (float)hf[tid * 4 + 0]
                  + wv.y * (float)hf[tid * 4 + 1]
                  + wv.z * (float)hf[tid * 4 + 2]
                  + wv.w * (float)hf[tid * 4 + 3];
#pragma unroll
        for (int off = 32; off > 0; off >>= 1)
            acc += __shfl_xor(acc, off, 64);
        if (lane == 0) red_f[wave] = acc;
        __syncthreads();
        if (tid == 0) {
            float s = bias[b];
#pragma unroll
            for (int w = 0; w < WPB; ++w) s += red_f[w];
            out[b] = s;
        }
    }
}

extern "C" void kernel_launch(void* const* d_in, const int* in_sizes, int n_in,
                              void* d_out, int out_size, void* d_ws, size_t ws_size,
                              hipStream_t stream) {
    const float* x    = (const float*)d_in[0];
    const float* Win  = (const float*)d_in[1];
    const float* W    = (const float*)d_in[2];
    const float* Wout = (const float*)d_in[3];
    const float* bias = (const float*)d_in[4];
    float* out = (float*)d_out;

    char* ws = (char*)d_ws;
    u64* hg0 = (u64*)ws;                   // 16 KB tagged granules, parity 0
    u64* hg1 = (u64*)(ws + 16384);         // 16 KB tagged granules, parity 1
    f16* Wh  = (f16*)(ws + 65536);         // 32 MB fp16 W

    // zero both granule buffers: h_0 = 0 with tag 0 comes for free
    hipMemsetAsync(ws, 0, 65536, stream);

    wconv_kernel<<<(R * (size_t)R) / (256 * 4), 256, 0, stream>>>(W, Wh);
    esn_kernel<<<NBLK, TPB, 0, stream>>>(x, Win, Wh, hg0, hg1,
                                         Wout, bias, out);
}

// Round 8
// 10933.452 us; speedup vs baseline: 2.7420x; 1.0814x over previous
//
#include <hip/hip_runtime.h>

typedef _Float16 f16;
typedef f16 f16x2 __attribute__((ext_vector_type(2)));
typedef f16 f16x4 __attribute__((ext_vector_type(4)));
typedef f16 f16x8 __attribute__((ext_vector_type(8)));
typedef float f32x4 __attribute__((ext_vector_type(4)));
typedef unsigned int u32;
typedef unsigned short u16;
typedef unsigned long long u64;

#define R 4096
#define IN_DIM 256
#define T_STEPS 4096
#define NBLK 128
#define TPB 1024
#define WPB 16
#define RPW 2                      // rows per wave
#define RPB (WPB * RPW)            // 32 rows per block
#define GPB (RPB / 2)              // 16 granules per block

// ---- W f32 -> fp16 conversion (re-run every call; deterministic) ----
__global__ void wconv_kernel(const float* __restrict__ W, f16* __restrict__ Wh) {
    size_t i = ((size_t)blockIdx.x * 256 + threadIdx.x) * 4;
    f32x4 v = *(const f32x4*)(W + i);
    f16x4 o = { (f16)v.x, (f16)v.y, (f16)v.z, (f16)v.w };
    *(f16x4*)(Wh + i) = o;
}

// ---- persistent scan: 128 blocks x 16 waves, 2 rows/wave, W in VGPRs.
// h exchanged as self-validating u64 granules (tag<<48 | 2 f16 rows),
// published as ONE 128B burst per block per step (16 u64 from wave 15). ----
__global__ __launch_bounds__(TPB) void esn_kernel(
    const float* __restrict__ x,      // [T][256]
    const float* __restrict__ Win,    // [R][256]
    const f16*   __restrict__ W,      // [R][R] fp16
    u64* hg0, u64* hg1,               // [R/2] tagged granules, double-buffered
    const float* __restrict__ Wout,   // [256][R]
    const float* __restrict__ bias,   // [256]
    float* __restrict__ out)          // [256]
{
    __shared__ f16   h_lds[2][R];     // 16 KB, parity double-buffered
    __shared__ float x_lds[2][IN_DIM];
    __shared__ u32   red_tag[RPB];    // tagged LDS relay words (32)
    __shared__ float red_f[WPB];      // epilogue reduction

    const int tid  = threadIdx.x;
    const int b    = blockIdx.x;
    const int wave = tid >> 6;
    const int lane = tid & 63;

    if (tid < RPB) red_tag[tid] = 0;  // LDS undefined across launches

    // one-time preload: 2 W rows (64 VGPRs) + 2 Win fragments (8 VGPRs)
    f16x8 wreg0[8], wreg1[8];
    {
        const f16* wrow0 = W + (size_t)(b * RPB + wave * RPW + 0) * R;
        const f16* wrow1 = W + (size_t)(b * RPB + wave * RPW + 1) * R;
#pragma unroll
        for (int c = 0; c < 8; ++c) {
            wreg0[c] = *(const f16x8*)(wrow0 + (c * 64 + lane) * 8);
            wreg1[c] = *(const f16x8*)(wrow1 + (c * 64 + lane) * 8);
        }
    }
    const f32x4 winreg0 = *(const f32x4*)(Win + (size_t)(b * RPB + wave * RPW + 0) * IN_DIM + lane * 4);
    const f32x4 winreg1 = *(const f32x4*)(Win + (size_t)(b * RPB + wave * RPW + 1) * IN_DIM + lane * 4);
    __syncthreads();

    for (int t = 0; t < T_STEPS; ++t) {
        const int p = t & 1;
        const u64* g_in  = p ? hg1 : hg0;
        u64*       g_out = p ? hg0 : hg1;

        // issue x[t] fragment load early; latency hides under the poll
        float xv = 0.f;
        if (tid < IN_DIM) xv = x[(size_t)t * IN_DIM + tid];

        // ---- fused poll+load, independent revalidation per granule ----
        {
            const u64* gp = g_in + (size_t)tid * 2;
            const u64 tt = (u64)(u32)t;
            u64 g0 = 0, g1 = 0;
            bool v0 = false, v1 = false;
            for (;;) {
                if (!v0) { g0 = __hip_atomic_load(gp,     __ATOMIC_RELAXED, __HIP_MEMORY_SCOPE_AGENT); v0 = (g0 >> 48) == tt; }
                if (!v1) { g1 = __hip_atomic_load(gp + 1, __ATOMIC_RELAXED, __HIP_MEMORY_SCOPE_AGENT); v1 = (g1 >> 48) == tt; }
                if (v0 & v1) break;
                __builtin_amdgcn_s_sleep(1);
            }
            u32* hl = (u32*)h_lds[p];
            hl[tid * 2 + 0] = (u32)g0;   // rows 4tid, 4tid+1 (packed f16x2)
            hl[tid * 2 + 1] = (u32)g1;   // rows 4tid+2, 4tid+3
        }
        if (tid < IN_DIM) x_lds[p][tid] = xv;
        __syncthreads();  // the ONLY barrier per step

        // ---- 2-row dot: 8 ds_read_b128 + 64 fdot2 (8 chains) ----
        float a00 = 0.f, a01 = 0.f, a02 = 0.f, a03 = 0.f;
        float a10 = 0.f, a11 = 0.f, a12 = 0.f, a13 = 0.f;
#pragma unroll
        for (int c = 0; c < 8; ++c) {
            const f16x8 hv = *(const f16x8*)(&h_lds[p][(c * 64 + lane) * 8]);
            const f16x2 h0 = { hv[0], hv[1] }, h1 = { hv[2], hv[3] };
            const f16x2 h2 = { hv[4], hv[5] }, h3 = { hv[6], hv[7] };
            {
                const f16x2 w0 = { wreg0[c][0], wreg0[c][1] }, w1 = { wreg0[c][2], wreg0[c][3] };
                const f16x2 w2 = { wreg0[c][4], wreg0[c][5] }, w3 = { wreg0[c][6], wreg0[c][7] };
                a00 = __builtin_amdgcn_fdot2(w0, h0, a00, false);
                a01 = __builtin_amdgcn_fdot2(w1, h1, a01, false);
                a02 = __builtin_amdgcn_fdot2(w2, h2, a02, false);
                a03 = __builtin_amdgcn_fdot2(w3, h3, a03, false);
            }
            {
                const f16x2 w0 = { wreg1[c][0], wreg1[c][1] }, w1 = { wreg1[c][2], wreg1[c][3] };
                const f16x2 w2 = { wreg1[c][4], wreg1[c][5] }, w3 = { wreg1[c][6], wreg1[c][7] };
                a10 = __builtin_amdgcn_fdot2(w0, h0, a10, false);
                a11 = __builtin_amdgcn_fdot2(w1, h1, a11, false);
                a12 = __builtin_amdgcn_fdot2(w2, h2, a12, false);
                a13 = __builtin_amdgcn_fdot2(w3, h3, a13, false);
            }
        }
        float acc0 = (a00 + a01) + (a02 + a03);
        float acc1 = (a10 + a11) + (a12 + a13);
        {
            const f32x4 xf = *(const f32x4*)(&x_lds[p][lane * 4]);
            acc0 = fmaf(winreg0.x, xf.x, acc0); acc0 = fmaf(winreg0.y, xf.y, acc0);
            acc0 = fmaf(winreg0.z, xf.z, acc0); acc0 = fmaf(winreg0.w, xf.w, acc0);
            acc1 = fmaf(winreg1.x, xf.x, acc1); acc1 = fmaf(winreg1.y, xf.y, acc1);
            acc1 = fmaf(winreg1.z, xf.z, acc1); acc1 = fmaf(winreg1.w, xf.w, acc1);
        }
#pragma unroll
        for (int off = 32; off > 0; off >>= 1) {
            acc0 += __shfl_xor(acc0, off, 64);
            acc1 += __shfl_xor(acc1, off, 64);
        }

        // ---- tagged LDS relay: lanes 0,1 post rows 2w,2w+1 ----
        {
            const float v = (lane == 0) ? acc0 : acc1;
            if (lane < 2) {
                f16 hf = (f16)tanhf(v);
                u16 bits;
                __builtin_memcpy(&bits, &hf, 2);
                __hip_atomic_store(&red_tag[wave * 2 + lane],
                                   ((u32)(t + 1) << 16) | (u32)bits,
                                   __ATOMIC_RELAXED, __HIP_MEMORY_SCOPE_WORKGROUP);
            }
        }

        // ---- wave 15: gather 32 relay words, pack 16 granules, ONE burst ----
        if (wave == WPB - 1) {
            u32 myw = 0;
            if (lane < RPB) {
                do {
                    myw = __hip_atomic_load(&red_tag[lane], __ATOMIC_RELAXED,
                                            __HIP_MEMORY_SCOPE_WORKGROUP);
                } while ((myw >> 16) != (u32)(t + 1));
            }
            const u32 wa = (u32)__shfl((int)myw, lane * 2,     64);
            const u32 wb = (u32)__shfl((int)myw, lane * 2 + 1, 64);
            if (lane < GPB) {
                const u64 g = ((u64)(u32)(t + 1) << 48)
                            | ((u64)(wb & 0xffffu) << 16)
                            | ((u64)(wa & 0xffffu));
                __hip_atomic_store(g_out + b * GPB + lane, g,
                                   __ATOMIC_RELAXED, __HIP_MEMORY_SCOPE_AGENT);
            }
        }
        // no trailing barrier: next poll + parity LDS double-buffer gate reuse
    }

    // ---- epilogue: poll h_T (tag = T_STEPS, parity 0), 2 outputs/block ----
    {
        const u64* gp = hg0 + (size_t)tid * 2;
        const u64 tt = (u64)(u32)T_STEPS;
        u64 g0, g1;
        for (;;) {
            g0 = __hip_atomic_load(gp,     __ATOMIC_RELAXED, __HIP_MEMORY_SCOPE_AGENT);
            g1 = __hip_atomic_load(gp + 1, __ATOMIC_RELAXED, __HIP_MEMORY_SCOPE_AGENT);
            if (((g0 >> 48) == tt) & ((g1 >> 48) == tt)) break;
            __builtin_amdgcn_s_sleep(1);
        }
        u32* hl = (u32*)h_lds[0];
        hl[tid * 2 + 0] = (u32)g0;
        hl[tid * 2 + 1] = (u32)g1;
    }
    __syncthreads();
#pragma unroll
    for (int oj = 0; oj < 2; ++oj) {
        const int j = b * 2 + oj;
        const float* worow = Wout + (size_t)j * R;
        const f32x4 wv = *(const f32x4*)(worow + tid * 4);
        const f16* hf = h_lds[0];
        float acc = wv.x * (float)hf[tid * 4 + 0]
                  + wv.y * (float)hf[tid * 4 + 1]
                  + wv.z * (float)hf[tid * 4 + 2]
                  + wv.w * (float)hf[tid * 4 + 3];
#pragma unroll
        for (int off = 32; off > 0; off >>= 1)
            acc += __shfl_xor(acc, off, 64);
        if (lane == 0) red_f[wave] = acc;
        __syncthreads();
        if (tid == 0) {
            float s = bias[j];
#pragma unroll
            for (int w = 0; w < WPB; ++w) s += red_f[w];
            out[j] = s;
        }
        __syncthreads();  // red_f reuse guard for oj=1
    }
}

extern "C" void kernel_launch(void* const* d_in, const int* in_sizes, int n_in,
                              void* d_out, int out_size, void* d_ws, size_t ws_size,
                              hipStream_t stream) {
    const float* x    = (const float*)d_in[0];
    const float* Win  = (const float*)d_in[1];
    const float* W    = (const float*)d_in[2];
    const float* Wout = (const float*)d_in[3];
    const float* bias = (const float*)d_in[4];
    float* out = (float*)d_out;

    char* ws = (char*)d_ws;
    u64* hg0 = (u64*)ws;                   // 16 KB tagged granules, parity 0
    u64* hg1 = (u64*)(ws + 16384);         // 16 KB tagged granules, parity 1
    f16* Wh  = (f16*)(ws + 65536);         // 32 MB fp16 W

    // zero both granule buffers: h_0 = 0 with tag 0 comes for free
    hipMemsetAsync(ws, 0, 65536, stream);

    wconv_kernel<<<(R * (size_t)R) / (256 * 4), 256, 0, stream>>>(W, Wh);
    esn_kernel<<<NBLK, TPB, 0, stream>>>(x, Win, Wh, hg0, hg1,
                                         Wout, bias, out);
}